// Round 25
// baseline (150.179 us; speedup 1.0000x reference)
//
#include <hip/hip_runtime.h>
#include <hip/hip_bf16.h>

#define E_DIM 1024
#define NHEAD 16
#define HDIM  64
#define BATCH 4
#define SEQ   2048
#define RQKV  (3 * E_DIM)

typedef __attribute__((ext_vector_type(8))) short bf16x8;
typedef __attribute__((ext_vector_type(4))) float f32x4;
typedef __attribute__((ext_vector_type(16))) float f32x16;

#define SCL2 0.04508422f   // (1/sqrt(E)) * log2(e) = log2(e)/32

static __device__ __forceinline__ unsigned short bits_of(__hip_bfloat16 h) {
    return *reinterpret_cast<unsigned short*>(&h);
}

static __device__ __forceinline__ void gload_lds16(const void* g, void* l) {
    __builtin_amdgcn_global_load_lds(
        (__attribute__((address_space(1))) void*)g,
        (__attribute__((address_space(3))) void*)l, 16, 0, 0);
}

// hardware packed f32->bf16 (RNE): dst.lo = bf16(a), dst.hi = bf16(b)
static __device__ __forceinline__ unsigned cvt_pk_bf16(float a, float b) {
    unsigned r;
    asm("v_cvt_pk_bf16_f32 %0, %1, %2" : "=v"(r) : "v"(a), "v"(b));
    return r;
}

// raw v_exp_f32 (2^x). Safe here: args bounded (<= ~3), -1e30 -> 0 natively.
static __device__ __forceinline__ float exp2_raw(float x) {
    float r;
    asm("v_exp_f32 %0, %1" : "=v"(r) : "v"(x));
    return r;
}

// ---------------- fused cast: x + 4 weights in one launch ------------------
__global__ void cast_all_kernel(
    const float* __restrict__ x,  const float* __restrict__ wq,
    const float* __restrict__ wk, const float* __restrict__ wv,
    const float* __restrict__ wo,
    __hip_bfloat16* __restrict__ xb, __hip_bfloat16* __restrict__ wqkvb,
    __hip_bfloat16* __restrict__ wob) {
    const int NX4 = (BATCH * SEQ * E_DIM) / 4;        // 2^21
    const int NW4 = (E_DIM * E_DIM) / 4;              // 2^18
    int id = blockIdx.x * 256 + threadIdx.x;

    const float* in;
    __hip_bfloat16* out;
    float scl = 1.0f;
    if (id < NX4) {
        in = x; out = xb;
    } else {
        const int r = id - NX4;
        const int wsel = r >> 18;
        id = r & (NW4 - 1);
        switch (wsel) {
            case 0: in = wq; out = wqkvb;            scl = SCL2; break;
            case 1: in = wk; out = wqkvb + NW4 * 4;  break;
            case 2: in = wv; out = wqkvb + NW4 * 8;  break;
            default: in = wo; out = wob;             break;
        }
    }
    float4 v = reinterpret_cast<const float4*>(in)[id];
    ushort4 u;
    u.x = bits_of(__float2bfloat16(v.x * scl));
    u.y = bits_of(__float2bfloat16(v.y * scl));
    u.z = bits_of(__float2bfloat16(v.z * scl));
    u.w = bits_of(__float2bfloat16(v.w * scl));
    reinterpret_cast<ushort4*>(out)[id] = u;
}

// ---------------- phased GEMM template: BM=128, BN=FN*64, BK=64 ------------
// (r24) 8 waves (2M x 4N), 2-buf LDS -> 2 blocks/CU; one sync per K-tile,
// no setprio fences.
template<int FN, int OUT_F32>
__global__ __launch_bounds__(512) void gemm_ph(
    const __hip_bfloat16* __restrict__ A,    // [M][K]
    const __hip_bfloat16* __restrict__ Bw,   // [N][K]
    void* __restrict__ Cv,                   // [M][N]
    int M, int N, int K) {
    constexpr int BN = FN * 64;
    __shared__ __align__(16) __hip_bfloat16 As[2][128 * 64];
    __shared__ __align__(16) __hip_bfloat16 Bs[2][BN * 64];

    const int nbx = gridDim.x;
    const int lin = blockIdx.y * nbx + blockIdx.x;
    const int cpx = (nbx * gridDim.y) >> 3;
    const int swz = (lin & 7) * cpx + (lin >> 3);
    const int mBase = (swz / nbx) * 128, nBase = (swz % nbx) * BN;

    const int t = threadIdx.x, lane = t & 63, w = t >> 6;
    const int wr = w >> 2, wc = w & 3;
    const int lr = lane & 15;
    const int lkb = (lane >> 4) * 16;

    f32x4 acc[4][FN];
#pragma unroll
    for (int i = 0; i < 4; ++i)
#pragma unroll
        for (int j = 0; j < FN; ++j) acc[i][j] = (f32x4){0.f, 0.f, 0.f, 0.f};

    const int NKT = K >> 6;

    auto STAGE = [&](int kt, int b) {
#pragma unroll
        for (int i = 0; i < 2; ++i) {
            const int q = i * 512 + t;
            const int r = q >> 3, cb = (q & 7) * 16;
            const char* src = (const char*)A +
                ((size_t)(mBase + r) * K + kt * 64) * 2 + (cb ^ ((r & 7) << 4));
            gload_lds16(src, (char*)&As[b][0] + q * 16);
        }
#pragma unroll
        for (int i = 0; i < FN; ++i) {
            const int q = i * 512 + t;
            const int r = q >> 3, cb = (q & 7) * 16;
            const char* src = (const char*)Bw +
                ((size_t)(nBase + r) * K + kt * 64) * 2 + (cb ^ ((r & 7) << 4));
            gload_lds16(src, (char*)&Bs[b][0] + q * 16);
        }
    };

    STAGE(0, 0);
    for (int kt = 0; kt < NKT; ++kt) {
        const int buf = kt & 1;
        asm volatile("s_waitcnt vmcnt(0)" ::: "memory");   // own DMA landed
        __builtin_amdgcn_s_barrier();                      // whole tile in LDS
        __builtin_amdgcn_sched_barrier(0);                 // no hoist above

        bf16x8 bfr[FN][2];
#pragma unroll
        for (int fn = 0; fn < FN; ++fn)
#pragma unroll
            for (int ks = 0; ks < 2; ++ks) {
                const int R = wc * (FN * 16) + fn * 16 + lr;
                const int addr = R * 128 + ((ks * 64 + lkb) ^ ((R & 7) << 4));
                bfr[fn][ks] = *reinterpret_cast<const bf16x8*>(
                    (const char*)&Bs[buf][0] + addr);
            }
        {
            bf16x8 af[2][2];
#pragma unroll
            for (int f = 0; f < 2; ++f)
#pragma unroll
                for (int ks = 0; ks < 2; ++ks) {
                    const int R = wr * 64 + f * 16 + lr;
                    const int addr = R * 128 + ((ks * 64 + lkb) ^ ((R & 7) << 4));
                    af[f][ks] = *reinterpret_cast<const bf16x8*>(
                        (const char*)&As[buf][0] + addr);
                }
            if (kt + 1 < NKT) STAGE(kt + 1, buf ^ 1);      // free buffer
#pragma unroll
            for (int f = 0; f < 2; ++f)
#pragma unroll
                for (int fn = 0; fn < FN; ++fn)
#pragma unroll
                    for (int ks = 0; ks < 2; ++ks)
                        acc[f][fn] = __builtin_amdgcn_mfma_f32_16x16x32_bf16(
                            af[f][ks], bfr[fn][ks], acc[f][fn], 0, 0, 0);
        }
        {
            bf16x8 af[2][2];
#pragma unroll
            for (int f = 0; f < 2; ++f)
#pragma unroll
                for (int ks = 0; ks < 2; ++ks) {
                    const int R = wr * 64 + (f + 2) * 16 + lr;
                    const int addr = R * 128 + ((ks * 64 + lkb) ^ ((R & 7) << 4));
                    af[f][ks] = *reinterpret_cast<const bf16x8*>(
                        (const char*)&As[buf][0] + addr);
                }
#pragma unroll
            for (int f = 0; f < 2; ++f)
#pragma unroll
                for (int fn = 0; fn < FN; ++fn)
#pragma unroll
                    for (int ks = 0; ks < 2; ++ks)
                        acc[f + 2][fn] = __builtin_amdgcn_mfma_f32_16x16x32_bf16(
                            af[f][ks], bfr[fn][ks], acc[f + 2][fn], 0, 0, 0);
        }
    }

#pragma unroll
    for (int fm = 0; fm < 4; ++fm)
#pragma unroll
        for (int fn = 0; fn < FN; ++fn)
#pragma unroll
            for (int v = 0; v < 4; ++v) {
                const int row = mBase + wr * 64 + fm * 16 + (lane >> 4) * 4 + v;
                const int col = nBase + wc * (FN * 16) + fn * 16 + lr;
                if (OUT_F32)
                    ((float*)Cv)[(size_t)row * N + col] = acc[fm][fn][v];
                else
                    ((__hip_bfloat16*)Cv)[(size_t)row * N + col] =
                        __float2bfloat16(acc[fm][fn][v]);
            }
}

// ---------------- flash attention (r24 + T14 V-prefetch) -------------------
// V regs for pair pr+1 are loaded right after the post-staging barrier and
// fly under the whole compute section; only pack/write remains between the
// staging barriers. K stays gload_lds (issued first, overlaps V pack).
__global__ __launch_bounds__(256) void attn_kernel(
    const __hip_bfloat16* __restrict__ QKV,   // [B*S][3E], Q|K|V blocks
    __hip_bfloat16* __restrict__ O) {         // [B*S][E]
    __shared__ __align__(16) __hip_bfloat16 Kl[2][64][64];
    __shared__ __align__(16) __hip_bfloat16 Vt[2][64][64];

    const int t = threadIdx.x, w = t >> 6, lane = t & 63;
    const int lq = lane & 31, hi = lane >> 5;

    const int id = blockIdx.x;
    const int c = id & 7, k = id >> 3;
    const int bh = (k & 7) * 8 + c;
    const int qq = k >> 3;
    const int qb = (qq & 4) ? (qq < 8 ? qq + 4 : qq - 12) : 15 - qq;
    const int b = bh >> 4, h = bh & 15;

    const size_t rb = (size_t)b * SEQ;
    const __hip_bfloat16* Qg = QKV + rb * RQKV + h * HDIM;
    const __hip_bfloat16* Kg = QKV + rb * RQKV + E_DIM + h * HDIM;
    const __hip_bfloat16* Vg = QKV + rb * RQKV + 2 * E_DIM + h * HDIM;

    const int kst_row  = w * 16 + (lane >> 3);
    const int kst_slot = lane & 7;
    const int vkp = t & 31, vd0 = (t >> 5) * 8;

    const int qw0 = qb * 128 + w * 32;
    const int qg  = qw0 + lq;

    bf16x8 aq[4];
#pragma unroll
    for (int d0 = 0; d0 < 4; ++d0)
        aq[d0] = *reinterpret_cast<const bf16x8*>(
            Qg + (size_t)qg * RQKV + d0 * 16 + hi * 8);

    f32x16 oa[2];
#pragma unroll
    for (int m = 0; m < 2; ++m)
#pragma unroll
        for (int r = 0; r < 16; ++r) oa[m][r] = 0.f;
    float l_run = 0.f;   // per-lane partial; single xor-32 merge in epilogue

    const int NP = qb + 1;   // pairs of 64-key tiles

    // ---- prologue: V regs for pair 0 ----
    bf16x8 va0, vb0, va1, vb1;
    {
        const __hip_bfloat16* vp0 = Vg + (size_t)(2 * vkp) * RQKV + vd0;
        const __hip_bfloat16* vp1 = vp0 + (size_t)64 * RQKV;
        va0 = *reinterpret_cast<const bf16x8*>(vp0);
        vb0 = *reinterpret_cast<const bf16x8*>(vp0 + RQKV);
        va1 = *reinterpret_cast<const bf16x8*>(vp1);
        vb1 = *reinterpret_cast<const bf16x8*>(vp1 + RQKV);
    }

    for (int pr = 0; pr < NP; ++pr) {
        const int k0a = pr * 128;
        __syncthreads();   // previous pair's LDS reads done (WAR)

        // --- issue K DMA for this pair (async; overlaps V pack below) ---
#pragma unroll
        for (int half = 0; half < 2; ++half)
#pragma unroll
            for (int i = 0; i < 2; ++i) {
                const int r = kst_row + i * 8;
                const char* src =
                    (const char*)(Kg + (size_t)(k0a + half * 64 + r) * RQKV) +
                    ((kst_slot * 16) ^ ((r & 7) << 4));
                gload_lds16(src, &Kl[half][w * 16 + i * 8][0]);
            }
        // --- write prefetched V regs -> Vt (v_perm pack + b32 writes) ---
        {
            union { bf16x8 v; unsigned u[4]; } A0, B0, A1, B1;
            A0.v = va0; B0.v = vb0; A1.v = va1; B1.v = vb1;
            char* vt0 = reinterpret_cast<char*>(&Vt[0][0][0]);
            char* vt1 = reinterpret_cast<char*>(&Vt[1][0][0]);
#pragma unroll
            for (int jw = 0; jw < 4; ++jw) {
                const int da = vd0 + 2 * jw, db = da + 1;
                const int offa = da * 128 + ((vkp * 4) ^ ((da & 7) << 4));
                const int offb = db * 128 + ((vkp * 4) ^ ((db & 7) << 4));
                *reinterpret_cast<unsigned*>(vt0 + offa) =
                    __builtin_amdgcn_perm(B0.u[jw], A0.u[jw], 0x05040100u);
                *reinterpret_cast<unsigned*>(vt0 + offb) =
                    __builtin_amdgcn_perm(B0.u[jw], A0.u[jw], 0x07060302u);
                *reinterpret_cast<unsigned*>(vt1 + offa) =
                    __builtin_amdgcn_perm(B1.u[jw], A1.u[jw], 0x05040100u);
                *reinterpret_cast<unsigned*>(vt1 + offb) =
                    __builtin_amdgcn_perm(B1.u[jw], A1.u[jw], 0x07060302u);
            }
        }
        __syncthreads();   // staging visible (drains vmcnt + lgkm)

        // --- T14: issue V loads for pair pr+1; fly under compute below ---
        if (pr + 1 < NP) {
            const __hip_bfloat16* vp0 =
                Vg + (size_t)((pr + 1) * 128 + 2 * vkp) * RQKV + vd0;
            const __hip_bfloat16* vp1 = vp0 + (size_t)64 * RQKV;
            va0 = *reinterpret_cast<const bf16x8*>(vp0);
            vb0 = *reinterpret_cast<const bf16x8*>(vp0 + RQKV);
            va1 = *reinterpret_cast<const bf16x8*>(vp1);
            vb1 = *reinterpret_cast<const bf16x8*>(vp1 + RQKV);
        }

#pragma unroll
        for (int half = 0; half < 2; ++half) {
            const int k0 = k0a + half * 64;
            if (k0 > qw0 + 31) continue;

            f32x16 sc2[2];
            const char* klbase = (const char*)&Kl[half][0][0];
#pragma unroll
            for (int tt = 0; tt < 2; ++tt) {
#pragma unroll
                for (int r = 0; r < 16; ++r) sc2[tt][r] = 0.f;
                const int kr = tt * 32 + lq;
                const char* kbase = klbase + kr * 128;
                const int swz = (kr & 7) << 4;
#pragma unroll
                for (int d0 = 0; d0 < 4; ++d0) {
                    bf16x8 ak = *reinterpret_cast<const bf16x8*>(
                        kbase + ((d0 * 32 + hi * 16) ^ swz));
                    sc2[tt] = __builtin_amdgcn_mfma_f32_32x32x16_bf16(
                        ak, aq[d0], sc2[tt], 0, 0, 0);
                }
            }
            if (k0 + 63 > qw0) {
#pragma unroll
                for (int tt = 0; tt < 2; ++tt)
#pragma unroll
                    for (int r = 0; r < 16; ++r) {
                        const int kgl = k0 + tt * 32 +
                                        (r & 3) + 8 * (r >> 2) + 4 * hi;
                        if (kgl > qg) sc2[tt][r] = -1e30f;
                    }
            }
            // no-max softmax (Q pre-scaled): P = exp2(s); per-lane partial l
            float rsum = 0.f;
#pragma unroll
            for (int tt = 0; tt < 2; ++tt) {
                float s0 = 0.f, s1 = 0.f, s2 = 0.f, s3 = 0.f;
#pragma unroll
                for (int r = 0; r < 16; r += 4) {
                    float p0 = exp2_raw(sc2[tt][r]);
                    float p1 = exp2_raw(sc2[tt][r + 1]);
                    float p2 = exp2_raw(sc2[tt][r + 2]);
                    float p3 = exp2_raw(sc2[tt][r + 3]);
                    sc2[tt][r] = p0; sc2[tt][r + 1] = p1;
                    sc2[tt][r + 2] = p2; sc2[tt][r + 3] = p3;
                    s0 += p0; s1 += p1; s2 += p2; s3 += p3;
                }
                rsum += (s0 + s1) + (s2 + s3);
            }
            l_run += rsum;   // no per-tile shfl; merged once at the end

            // P -> bf16 B-frags: v_cvt_pk_bf16_f32 + permlane32_swap; PV
            const char* vtbase = (const char*)&Vt[half][0][0];
#pragma unroll
            for (int tt = 0; tt < 2; ++tt)
#pragma unroll
                for (int sl = 0; sl < 2; ++sl) {
                    const int rbs = sl * 8;
                    const unsigned wA = cvt_pk_bf16(sc2[tt][rbs + 0], sc2[tt][rbs + 1]);
                    const unsigned wB = cvt_pk_bf16(sc2[tt][rbs + 2], sc2[tt][rbs + 3]);
                    const unsigned wC = cvt_pk_bf16(sc2[tt][rbs + 4], sc2[tt][rbs + 5]);
                    const unsigned wD = cvt_pk_bf16(sc2[tt][rbs + 6], sc2[tt][rbs + 7]);
                    const auto pA = __builtin_amdgcn_permlane32_swap(wA, wC, false, false);
                    const auto pB = __builtin_amdgcn_permlane32_swap(wB, wD, false, false);
                    union { unsigned u[4]; bf16x8 v; } pf;
                    pf.u[0] = pA[0]; pf.u[1] = pB[0];
                    pf.u[2] = pA[1]; pf.u[3] = pB[1];
                    const int ks = tt * 2 + sl;
#pragma unroll
                    for (int m = 0; m < 2; ++m) {
                        const int dr = m * 32 + lq;
                        bf16x8 av = *reinterpret_cast<const bf16x8*>(
                            vtbase + dr * 128 +
                            ((ks * 32 + hi * 16) ^ ((dr & 7) << 4)));
                        oa[m] = __builtin_amdgcn_mfma_f32_32x32x16_bf16(
                            av, pf.v, oa[m], 0, 0, 0);
                    }
                }
        }
    }

    // --- epilogue: single cross-half l merge, normalize, store ---
    l_run += __shfl_xor(l_run, 32);
    const float inv = 1.f / l_run;
    __hip_bfloat16* Orow = O + (rb + qg) * E_DIM + h * HDIM;
#pragma unroll
    for (int m = 0; m < 2; ++m)
#pragma unroll
        for (int q4 = 0; q4 < 4; ++q4) {
            ushort4 pk;
            pk.x = bits_of(__float2bfloat16(oa[m][q4 * 4 + 0] * inv));
            pk.y = bits_of(__float2bfloat16(oa[m][q4 * 4 + 1] * inv));
            pk.z = bits_of(__float2bfloat16(oa[m][q4 * 4 + 2] * inv));
            pk.w = bits_of(__float2bfloat16(oa[m][q4 * 4 + 3] * inv));
            *reinterpret_cast<ushort4*>(Orow + m * 32 + q4 * 8 + 4 * hi) = pk;
        }
}

// ---------------- launch ----------------
extern "C" void kernel_launch(void* const* d_in, const int* in_sizes, int n_in,
                              void* d_out, int out_size, void* d_ws, size_t ws_size,
                              hipStream_t stream) {
    const float* x  = (const float*)d_in[0];
    const float* wq = (const float*)d_in[1];
    const float* wk = (const float*)d_in[2];
    const float* wv = (const float*)d_in[3];
    const float* wo = (const float*)d_in[4];

    const size_t SZ_X = (size_t)BATCH * SEQ * E_DIM;   // 8388608
    const size_t SZ_W = (size_t)E_DIM * E_DIM;         // 1048576

    char* p = (char*)d_ws;
    __hip_bfloat16* xb    = (__hip_bfloat16*)p; p += SZ_X * 2;
    __hip_bfloat16* wqkvb = (__hip_bfloat16*)p; p += 3 * SZ_W * 2;   // [3E][E]
    __hip_bfloat16* wob   = (__hip_bfloat16*)p; p += SZ_W * 2;
    __hip_bfloat16* QKVb  = (__hip_bfloat16*)p; p += SZ_X * 3 * 2;   // [M][3E]
    __hip_bfloat16* attb  = (__hip_bfloat16*)p; p += SZ_X * 2;

    cast_all_kernel<<<dim3(12288), 256, 0, stream>>>(
        x, wq, wk, wv, wo, xb, wqkvb, wob);

    const int M = BATCH * SEQ;  // 8192
    gemm_ph<3, 0><<<dim3(RQKV / 192, M / 128), 512, 0, stream>>>(
        xb, wqkvb, QKVb, M, RQKV, E_DIM);

    attn_kernel<<<dim3(1024), 256, 0, stream>>>(QKVb, attb);

    gemm_ph<2, 1><<<dim3(E_DIM / 128, M / 128), 512, 0, stream>>>(
        attb, wob, d_out, M, E_DIM, E_DIM);
}

// Round 26
// 148.961 us; speedup vs baseline: 1.0082x; 1.0082x over previous
//
#include <hip/hip_runtime.h>
#include <hip/hip_bf16.h>

#define E_DIM 1024
#define NHEAD 16
#define HDIM  64
#define BATCH 4
#define SEQ   2048
#define RQKV  (3 * E_DIM)

typedef __attribute__((ext_vector_type(8))) short bf16x8;
typedef __attribute__((ext_vector_type(4))) float f32x4;
typedef __attribute__((ext_vector_type(16))) float f32x16;

#define SCL2 0.04508422f   // (1/sqrt(E)) * log2(e) = log2(e)/32

static __device__ __forceinline__ unsigned short bits_of(__hip_bfloat16 h) {
    return *reinterpret_cast<unsigned short*>(&h);
}

static __device__ __forceinline__ void gload_lds16(const void* g, void* l) {
    __builtin_amdgcn_global_load_lds(
        (__attribute__((address_space(1))) void*)g,
        (__attribute__((address_space(3))) void*)l, 16, 0, 0);
}

// hardware packed f32->bf16 (RNE): dst.lo = bf16(a), dst.hi = bf16(b)
static __device__ __forceinline__ unsigned cvt_pk_bf16(float a, float b) {
    unsigned r;
    asm("v_cvt_pk_bf16_f32 %0, %1, %2" : "=v"(r) : "v"(a), "v"(b));
    return r;
}

// raw v_exp_f32 (2^x). Safe here: args bounded (<= ~3), -1e30 -> 0 natively.
static __device__ __forceinline__ float exp2_raw(float x) {
    float r;
    asm("v_exp_f32 %0, %1" : "=v"(r) : "v"(x));
    return r;
}

// ---------------- fused cast: x + 4 weights in one launch ------------------
__global__ void cast_all_kernel(
    const float* __restrict__ x,  const float* __restrict__ wq,
    const float* __restrict__ wk, const float* __restrict__ wv,
    const float* __restrict__ wo,
    __hip_bfloat16* __restrict__ xb, __hip_bfloat16* __restrict__ wqkvb,
    __hip_bfloat16* __restrict__ wob) {
    const int NX4 = (BATCH * SEQ * E_DIM) / 4;        // 2^21
    const int NW4 = (E_DIM * E_DIM) / 4;              // 2^18
    int id = blockIdx.x * 256 + threadIdx.x;

    const float* in;
    __hip_bfloat16* out;
    float scl = 1.0f;
    if (id < NX4) {
        in = x; out = xb;
    } else {
        const int r = id - NX4;
        const int wsel = r >> 18;
        id = r & (NW4 - 1);
        switch (wsel) {
            case 0: in = wq; out = wqkvb;            scl = SCL2; break;
            case 1: in = wk; out = wqkvb + NW4 * 4;  break;
            case 2: in = wv; out = wqkvb + NW4 * 8;  break;
            default: in = wo; out = wob;             break;
        }
    }
    float4 v = reinterpret_cast<const float4*>(in)[id];
    ushort4 u;
    u.x = bits_of(__float2bfloat16(v.x * scl));
    u.y = bits_of(__float2bfloat16(v.y * scl));
    u.z = bits_of(__float2bfloat16(v.z * scl));
    u.w = bits_of(__float2bfloat16(v.w * scl));
    reinterpret_cast<ushort4*>(out)[id] = u;
}

// ---------------- phased GEMM template: BM=128, BN=FN*64, BK=64 ------------
// 8 waves (2M x 4N), 2-buf LDS -> 2 blocks/CU. One sync point per K-tile:
// entry {vmcnt(0); barrier; sched_barrier}. No setprio fences: the compiler
// may interleave phase-1 ds_reads into phase-0's MFMA shadow.
template<int FN, int OUT_F32>
__global__ __launch_bounds__(512) void gemm_ph(
    const __hip_bfloat16* __restrict__ A,    // [M][K]
    const __hip_bfloat16* __restrict__ Bw,   // [N][K]
    void* __restrict__ Cv,                   // [M][N]
    int M, int N, int K) {
    constexpr int BN = FN * 64;
    __shared__ __align__(16) __hip_bfloat16 As[2][128 * 64];
    __shared__ __align__(16) __hip_bfloat16 Bs[2][BN * 64];

    const int nbx = gridDim.x;
    const int lin = blockIdx.y * nbx + blockIdx.x;
    const int cpx = (nbx * gridDim.y) >> 3;
    const int swz = (lin & 7) * cpx + (lin >> 3);
    const int mBase = (swz / nbx) * 128, nBase = (swz % nbx) * BN;

    const int t = threadIdx.x, lane = t & 63, w = t >> 6;
    const int wr = w >> 2, wc = w & 3;
    const int lr = lane & 15;
    const int lkb = (lane >> 4) * 16;

    f32x4 acc[4][FN];
#pragma unroll
    for (int i = 0; i < 4; ++i)
#pragma unroll
        for (int j = 0; j < FN; ++j) acc[i][j] = (f32x4){0.f, 0.f, 0.f, 0.f};

    const int NKT = K >> 6;

    auto STAGE = [&](int kt, int b) {
#pragma unroll
        for (int i = 0; i < 2; ++i) {
            const int q = i * 512 + t;
            const int r = q >> 3, cb = (q & 7) * 16;
            const char* src = (const char*)A +
                ((size_t)(mBase + r) * K + kt * 64) * 2 + (cb ^ ((r & 7) << 4));
            gload_lds16(src, (char*)&As[b][0] + q * 16);
        }
#pragma unroll
        for (int i = 0; i < FN; ++i) {
            const int q = i * 512 + t;
            const int r = q >> 3, cb = (q & 7) * 16;
            const char* src = (const char*)Bw +
                ((size_t)(nBase + r) * K + kt * 64) * 2 + (cb ^ ((r & 7) << 4));
            gload_lds16(src, (char*)&Bs[b][0] + q * 16);
        }
    };

    STAGE(0, 0);
    for (int kt = 0; kt < NKT; ++kt) {
        const int buf = kt & 1;
        asm volatile("s_waitcnt vmcnt(0)" ::: "memory");   // own DMA landed
        __builtin_amdgcn_s_barrier();                      // whole tile in LDS
        __builtin_amdgcn_sched_barrier(0);                 // no hoist above

        bf16x8 bfr[FN][2];
#pragma unroll
        for (int fn = 0; fn < FN; ++fn)
#pragma unroll
            for (int ks = 0; ks < 2; ++ks) {
                const int R = wc * (FN * 16) + fn * 16 + lr;
                const int addr = R * 128 + ((ks * 64 + lkb) ^ ((R & 7) << 4));
                bfr[fn][ks] = *reinterpret_cast<const bf16x8*>(
                    (const char*)&Bs[buf][0] + addr);
            }
        {
            bf16x8 af[2][2];
#pragma unroll
            for (int f = 0; f < 2; ++f)
#pragma unroll
                for (int ks = 0; ks < 2; ++ks) {
                    const int R = wr * 64 + f * 16 + lr;
                    const int addr = R * 128 + ((ks * 64 + lkb) ^ ((R & 7) << 4));
                    af[f][ks] = *reinterpret_cast<const bf16x8*>(
                        (const char*)&As[buf][0] + addr);
                }
            if (kt + 1 < NKT) STAGE(kt + 1, buf ^ 1);      // free buffer
#pragma unroll
            for (int f = 0; f < 2; ++f)
#pragma unroll
                for (int fn = 0; fn < FN; ++fn)
#pragma unroll
                    for (int ks = 0; ks < 2; ++ks)
                        acc[f][fn] = __builtin_amdgcn_mfma_f32_16x16x32_bf16(
                            af[f][ks], bfr[fn][ks], acc[f][fn], 0, 0, 0);
        }
        {
            bf16x8 af[2][2];
#pragma unroll
            for (int f = 0; f < 2; ++f)
#pragma unroll
                for (int ks = 0; ks < 2; ++ks) {
                    const int R = wr * 64 + (f + 2) * 16 + lr;
                    const int addr = R * 128 + ((ks * 64 + lkb) ^ ((R & 7) << 4));
                    af[f][ks] = *reinterpret_cast<const bf16x8*>(
                        (const char*)&As[buf][0] + addr);
                }
#pragma unroll
            for (int f = 0; f < 2; ++f)
#pragma unroll
                for (int fn = 0; fn < FN; ++fn)
#pragma unroll
                    for (int ks = 0; ks < 2; ++ks)
                        acc[f + 2][fn] = __builtin_amdgcn_mfma_f32_16x16x32_bf16(
                            af[f][ks], bfr[fn][ks], acc[f + 2][fn], 0, 0, 0);
        }
    }

#pragma unroll
    for (int fm = 0; fm < 4; ++fm)
#pragma unroll
        for (int fn = 0; fn < FN; ++fn)
#pragma unroll
            for (int v = 0; v < 4; ++v) {
                const int row = mBase + wr * 64 + fm * 16 + (lane >> 4) * 4 + v;
                const int col = nBase + wc * (FN * 16) + fn * 16 + lr;
                if (OUT_F32)
                    ((float*)Cv)[(size_t)row * N + col] = acc[fm][fn][v];
                else
                    ((__hip_bfloat16*)Cv)[(size_t)row * N + col] =
                        __float2bfloat16(acc[fm][fn][v]);
            }
}

// ---------------- flash attention (r20/21 structure) -----------------------
__global__ __launch_bounds__(256) void attn_kernel(
    const __hip_bfloat16* __restrict__ QKV,   // [B*S][3E], Q|K|V blocks
    __hip_bfloat16* __restrict__ O) {         // [B*S][E]
    __shared__ __align__(16) __hip_bfloat16 Kl[2][64][64];
    __shared__ __align__(16) __hip_bfloat16 Vt[2][64][64];

    const int t = threadIdx.x, w = t >> 6, lane = t & 63;
    const int lq = lane & 31, hi = lane >> 5;

    const int id = blockIdx.x;
    const int c = id & 7, k = id >> 3;
    const int bh = (k & 7) * 8 + c;
    const int qq = k >> 3;
    const int qb = (qq & 4) ? (qq < 8 ? qq + 4 : qq - 12) : 15 - qq;
    const int b = bh >> 4, h = bh & 15;

    const size_t rb = (size_t)b * SEQ;
    const __hip_bfloat16* Qg = QKV + rb * RQKV + h * HDIM;
    const __hip_bfloat16* Kg = QKV + rb * RQKV + E_DIM + h * HDIM;
    const __hip_bfloat16* Vg = QKV + rb * RQKV + 2 * E_DIM + h * HDIM;

    const int kst_row  = w * 16 + (lane >> 3);
    const int kst_slot = lane & 7;
    const int vkp = t & 31, vd0 = (t >> 5) * 8;

    const int qw0 = qb * 128 + w * 32;
    const int qg  = qw0 + lq;

    bf16x8 aq[4];
#pragma unroll
    for (int d0 = 0; d0 < 4; ++d0)
        aq[d0] = *reinterpret_cast<const bf16x8*>(
            Qg + (size_t)qg * RQKV + d0 * 16 + hi * 8);

    f32x16 oa[2];
#pragma unroll
    for (int m = 0; m < 2; ++m)
#pragma unroll
        for (int r = 0; r < 16; ++r) oa[m][r] = 0.f;
    float l_run = 0.f;   // per-lane partial; single xor-32 merge in epilogue

    const int NP = qb + 1;   // pairs of 64-key tiles
    for (int pr = 0; pr < NP; ++pr) {
        const int k0a = pr * 128;
        __syncthreads();

#pragma unroll
        for (int half = 0; half < 2; ++half)
#pragma unroll
            for (int i = 0; i < 2; ++i) {
                const int r = kst_row + i * 8;
                const char* src =
                    (const char*)(Kg + (size_t)(k0a + half * 64 + r) * RQKV) +
                    ((kst_slot * 16) ^ ((r & 7) << 4));
                gload_lds16(src, &Kl[half][w * 16 + i * 8][0]);
            }
        // --- stage V transposed for both tiles (v_perm pack + b32 writes) ---
        {
            const __hip_bfloat16* vp0 =
                Vg + (size_t)(k0a + 2 * vkp) * RQKV + vd0;
            const __hip_bfloat16* vp1 = vp0 + (size_t)64 * RQKV;
            union { bf16x8 v; unsigned u[4]; } A0, B0, A1, B1;
            A0.v = *reinterpret_cast<const bf16x8*>(vp0);
            B0.v = *reinterpret_cast<const bf16x8*>(vp0 + RQKV);
            A1.v = *reinterpret_cast<const bf16x8*>(vp1);
            B1.v = *reinterpret_cast<const bf16x8*>(vp1 + RQKV);
            char* vt0 = reinterpret_cast<char*>(&Vt[0][0][0]);
            char* vt1 = reinterpret_cast<char*>(&Vt[1][0][0]);
#pragma unroll
            for (int jw = 0; jw < 4; ++jw) {
                const int da = vd0 + 2 * jw, db = da + 1;
                const int offa = da * 128 + ((vkp * 4) ^ ((da & 7) << 4));
                const int offb = db * 128 + ((vkp * 4) ^ ((db & 7) << 4));
                *reinterpret_cast<unsigned*>(vt0 + offa) =
                    __builtin_amdgcn_perm(B0.u[jw], A0.u[jw], 0x05040100u);
                *reinterpret_cast<unsigned*>(vt0 + offb) =
                    __builtin_amdgcn_perm(B0.u[jw], A0.u[jw], 0x07060302u);
                *reinterpret_cast<unsigned*>(vt1 + offa) =
                    __builtin_amdgcn_perm(B1.u[jw], A1.u[jw], 0x05040100u);
                *reinterpret_cast<unsigned*>(vt1 + offb) =
                    __builtin_amdgcn_perm(B1.u[jw], A1.u[jw], 0x07060302u);
            }
        }
        __syncthreads();

#pragma unroll
        for (int half = 0; half < 2; ++half) {
            const int k0 = k0a + half * 64;
            if (k0 > qw0 + 31) continue;

            f32x16 sc2[2];
            const char* klbase = (const char*)&Kl[half][0][0];
#pragma unroll
            for (int tt = 0; tt < 2; ++tt) {
#pragma unroll
                for (int r = 0; r < 16; ++r) sc2[tt][r] = 0.f;
                const int kr = tt * 32 + lq;
                const char* kbase = klbase + kr * 128;
                const int swz = (kr & 7) << 4;
#pragma unroll
                for (int d0 = 0; d0 < 4; ++d0) {
                    bf16x8 ak = *reinterpret_cast<const bf16x8*>(
                        kbase + ((d0 * 32 + hi * 16) ^ swz));
                    sc2[tt] = __builtin_amdgcn_mfma_f32_32x32x16_bf16(
                        ak, aq[d0], sc2[tt], 0, 0, 0);
                }
            }
            if (k0 + 63 > qw0) {
#pragma unroll
                for (int tt = 0; tt < 2; ++tt)
#pragma unroll
                    for (int r = 0; r < 16; ++r) {
                        const int kgl = k0 + tt * 32 +
                                        (r & 3) + 8 * (r >> 2) + 4 * hi;
                        if (kgl > qg) sc2[tt][r] = -1e30f;
                    }
            }
            // no-max softmax (Q pre-scaled): P = exp2(s); per-lane partial l
            float rsum = 0.f;
#pragma unroll
            for (int tt = 0; tt < 2; ++tt) {
                float s0 = 0.f, s1 = 0.f, s2 = 0.f, s3 = 0.f;
#pragma unroll
                for (int r = 0; r < 16; r += 4) {
                    float p0 = exp2_raw(sc2[tt][r]);
                    float p1 = exp2_raw(sc2[tt][r + 1]);
                    float p2 = exp2_raw(sc2[tt][r + 2]);
                    float p3 = exp2_raw(sc2[tt][r + 3]);
                    sc2[tt][r] = p0; sc2[tt][r + 1] = p1;
                    sc2[tt][r + 2] = p2; sc2[tt][r + 3] = p3;
                    s0 += p0; s1 += p1; s2 += p2; s3 += p3;
                }
                rsum += (s0 + s1) + (s2 + s3);
            }
            l_run += rsum;   // no per-tile shfl; merged once at the end

            // P -> bf16 B-frags: v_cvt_pk_bf16_f32 + permlane32_swap; PV
            const char* vtbase = (const char*)&Vt[half][0][0];
#pragma unroll
            for (int tt = 0; tt < 2; ++tt)
#pragma unroll
                for (int sl = 0; sl < 2; ++sl) {
                    const int rbs = sl * 8;
                    const unsigned wA = cvt_pk_bf16(sc2[tt][rbs + 0], sc2[tt][rbs + 1]);
                    const unsigned wB = cvt_pk_bf16(sc2[tt][rbs + 2], sc2[tt][rbs + 3]);
                    const unsigned wC = cvt_pk_bf16(sc2[tt][rbs + 4], sc2[tt][rbs + 5]);
                    const unsigned wD = cvt_pk_bf16(sc2[tt][rbs + 6], sc2[tt][rbs + 7]);
                    const auto pA = __builtin_amdgcn_permlane32_swap(wA, wC, false, false);
                    const auto pB = __builtin_amdgcn_permlane32_swap(wB, wD, false, false);
                    union { unsigned u[4]; bf16x8 v; } pf;
                    pf.u[0] = pA[0]; pf.u[1] = pB[0];
                    pf.u[2] = pA[1]; pf.u[3] = pB[1];
                    const int ks = tt * 2 + sl;
#pragma unroll
                    for (int m = 0; m < 2; ++m) {
                        const int dr = m * 32 + lq;
                        bf16x8 av = *reinterpret_cast<const bf16x8*>(
                            vtbase + dr * 128 +
                            ((ks * 32 + hi * 16) ^ ((dr & 7) << 4)));
                        oa[m] = __builtin_amdgcn_mfma_f32_32x32x16_bf16(
                            av, pf.v, oa[m], 0, 0, 0);
                    }
                }
        }
    }

    // --- epilogue: single cross-half l merge, normalize, store ---
    l_run += __shfl_xor(l_run, 32);
    const float inv = 1.f / l_run;
    __hip_bfloat16* Orow = O + (rb + qg) * E_DIM + h * HDIM;
#pragma unroll
    for (int m = 0; m < 2; ++m)
#pragma unroll
        for (int q4 = 0; q4 < 4; ++q4) {
            ushort4 pk;
            pk.x = bits_of(__float2bfloat16(oa[m][q4 * 4 + 0] * inv));
            pk.y = bits_of(__float2bfloat16(oa[m][q4 * 4 + 1] * inv));
            pk.z = bits_of(__float2bfloat16(oa[m][q4 * 4 + 2] * inv));
            pk.w = bits_of(__float2bfloat16(oa[m][q4 * 4 + 3] * inv));
            *reinterpret_cast<ushort4*>(Orow + m * 32 + q4 * 8 + 4 * hi) = pk;
        }
}

// ---------------- launch ----------------
extern "C" void kernel_launch(void* const* d_in, const int* in_sizes, int n_in,
                              void* d_out, int out_size, void* d_ws, size_t ws_size,
                              hipStream_t stream) {
    const float* x  = (const float*)d_in[0];
    const float* wq = (const float*)d_in[1];
    const float* wk = (const float*)d_in[2];
    const float* wv = (const float*)d_in[3];
    const float* wo = (const float*)d_in[4];

    const size_t SZ_X = (size_t)BATCH * SEQ * E_DIM;   // 8388608
    const size_t SZ_W = (size_t)E_DIM * E_DIM;         // 1048576

    char* p = (char*)d_ws;
    __hip_bfloat16* xb    = (__hip_bfloat16*)p; p += SZ_X * 2;
    __hip_bfloat16* wqkvb = (__hip_bfloat16*)p; p += 3 * SZ_W * 2;   // [3E][E]
    __hip_bfloat16* wob   = (__hip_bfloat16*)p; p += SZ_W * 2;
    __hip_bfloat16* QKVb  = (__hip_bfloat16*)p; p += SZ_X * 3 * 2;   // [M][3E]
    __hip_bfloat16* attb  = (__hip_bfloat16*)p; p += SZ_X * 2;

    cast_all_kernel<<<dim3(12288), 256, 0, stream>>>(
        x, wq, wk, wv, wo, xb, wqkvb, wob);

    const int M = BATCH * SEQ;  // 8192
    gemm_ph<3, 0><<<dim3(RQKV / 192, M / 128), 512, 0, stream>>>(
        xb, wqkvb, QKVb, M, RQKV, E_DIM);

    attn_kernel<<<dim3(1024), 256, 0, stream>>>(QKVb, attb);

    gemm_ph<2, 1><<<dim3(E_DIM / 128, M / 128), 512, 0, stream>>>(
        attb, wob, d_out, M, E_DIM, E_DIM);
}